// Round 7
// baseline (213.484 us; speedup 1.0000x reference)
//
#include <hip/hip_runtime.h>
#include <hip/hip_bf16.h>
#include <cstddef>
#include <cstdint>

#define HID 1024
#define NHEADS 16
#define HDIM 64
#define BATCH 2
#define SEQ 2048
#define MROWS (BATCH * SEQ)   // 4096
#define BHT (BATCH * NHEADS)  // 32

typedef __attribute__((ext_vector_type(8))) short s8v;   // 8 x bf16 (4 VGPR)
typedef __attribute__((ext_vector_type(4))) float f4v;   // MFMA C/D frag

__device__ __forceinline__ unsigned short f2bf(float x) {
    union { float f; unsigned int u; } c; c.f = x;
    return (unsigned short)((c.u + 0x7fffu + ((c.u >> 16) & 1u)) >> 16);  // RTN
}
__device__ __forceinline__ float bf2f(unsigned short b) {
    union { float f; unsigned int u; } c; c.u = ((unsigned int)b) << 16;
    return c.f;
}
__device__ __forceinline__ unsigned int pkbf(float a, float b) {
    __hip_bfloat162 h = __float22bfloat162_rn(float2{a, b});  // x -> low 16
    union { __hip_bfloat162 v; unsigned int u; } c; c.v = h; return c.u;
}
__device__ __forceinline__ float bflo(unsigned int w) {
    union { unsigned int u; float f; } c; c.u = w << 16; return c.f;
}
__device__ __forceinline__ float bfhi(unsigned int w) {
    union { unsigned int u; float f; } c; c.u = w & 0xffff0000u; return c.f;
}

__device__ __forceinline__ void lds_load16(void* lds, const void* g) {
    __builtin_amdgcn_global_load_lds(
        (const __attribute__((address_space(1))) void*)g,
        (__attribute__((address_space(3))) void*)lds, 16, 0, 0);
}

// ---------------- Stage 0a: hs fp32 -> bf16 hi/lo, layout [m][k] ----------------
__global__ __launch_bounds__(256) void conv_hs_kernel(
    const float* __restrict__ hs,
    unsigned short* __restrict__ Ah, unsigned short* __restrict__ Al)
{
    const int idx = (blockIdx.x * 256 + threadIdx.x) * 4;
    float4 v = *(const float4*)&hs[idx];
    float x[4] = {v.x, v.y, v.z, v.w};
    union { unsigned short u[4]; unsigned long long q; } h, l;
#pragma unroll
    for (int j = 0; j < 4; ++j) {
        unsigned short hh = f2bf(x[j]);
        h.u[j] = hh;
        l.u[j] = f2bf(x[j] - bf2f(hh));
    }
    *(unsigned long long*)&Ah[idx] = h.q;
    *(unsigned long long*)&Al[idx] = l.q;
}

// ---------------- Stage 0b: W [k][n] -> W^T [n][k] bf16 hi/lo ----------------
__global__ __launch_bounds__(256) void conv_wt_kernel(
    const float* __restrict__ Wq, const float* __restrict__ Wk,
    const float* __restrict__ Wv,
    unsigned short* __restrict__ WTh, unsigned short* __restrict__ WTl)
{
    const int z = blockIdx.z;
    const float* W = (z == 0) ? Wq : (z == 1) ? Wk : Wv;
    unsigned short* th = WTh + (size_t)z * HID * HID;
    unsigned short* tl = WTl + (size_t)z * HID * HID;

    __shared__ float tile[64][65];
    const int t = threadIdx.x;
    const int kb = blockIdx.y * 64, nb = blockIdx.x * 64;
    const int c4 = (t & 15) * 4;
    const int r0 = t >> 4;

#pragma unroll
    for (int i = 0; i < 4; ++i) {
        int r = r0 + i * 16;
        float4 v = *(const float4*)&W[(size_t)(kb + r) * HID + nb + c4];
        tile[r][c4 + 0] = v.x; tile[r][c4 + 1] = v.y;
        tile[r][c4 + 2] = v.z; tile[r][c4 + 3] = v.w;
    }
    __syncthreads();
#pragma unroll
    for (int i = 0; i < 4; ++i) {
        int n = r0 + i * 16;
        union { unsigned short u[4]; unsigned long long q; } h, l;
#pragma unroll
        for (int j = 0; j < 4; ++j) {
            float x = tile[c4 + j][n];
            unsigned short hh = f2bf(x);
            h.u[j] = hh;
            l.u[j] = f2bf(x - bf2f(hh));
        }
        size_t base = (size_t)(nb + n) * HID + kb + c4;
        *(unsigned long long*)&th[base] = h.q;
        if (z == 0) *(unsigned long long*)&tl[base] = l.q;
    }
}

// ---------------- Stage 1: QKV projection via split-bf16 MFMA ----------------
// z=0 (Q): 3-term, BK=32, 16 steps, out Qhi/Qlo prescaled 0.125*log2(e).
// z=1 (K): 1-term, BK=64, 8 steps (XOR-swizzled LDS), out Khi [bh][s][d].
// z=2 (V): 1-term, BK=64, out VT [bh][d][s].
#define GBM 128
#define GBN 128
#define QSCALE 0.18033688011112042f   // 0.125 * log2(e)

__global__ __launch_bounds__(256) void qkv_mfma_kernel(
    const unsigned short* __restrict__ Ah, const unsigned short* __restrict__ Al,
    const unsigned short* __restrict__ WTh, const unsigned short* __restrict__ WTl,
    const float* __restrict__ bq, const float* __restrict__ bk,
    const float* __restrict__ bv,
    unsigned short* __restrict__ Qhi, unsigned short* __restrict__ Qlo,
    unsigned short* __restrict__ Khi, unsigned short* __restrict__ VTg)
{
    const int z = blockIdx.z;
    const float* bias = (z == 0) ? bq : (z == 1) ? bk : bv;
    const unsigned short* Bh = WTh + (size_t)z * HID * HID;
    const unsigned short* Bl = WTl + (size_t)z * HID * HID;

    __shared__ unsigned short smem[16384];  // 32 KB, dual-purpose by z

    const int t = threadIdx.x;
    const int wave = t >> 6, lane = t & 63, quad = lane >> 4, l15 = lane & 15;
    const int sw = l15 & 7;
    const int wm = wave >> 1, wn = wave & 1;
    const int rowBase = blockIdx.x * GBM;   // M tile (x-major: A-sharing on one XCD)
    const int colBase = blockIdx.y * GBN;   // N tile

    f4v acc[4][4];
#pragma unroll
    for (int mf = 0; mf < 4; ++mf)
#pragma unroll
        for (int nf = 0; nf < 4; ++nf) acc[mf][nf] = (f4v){0.f, 0.f, 0.f, 0.f};

    if (z == 0) {
        // ---------- 3-term Q path, BK=32 ----------
        unsigned short* AhS = smem;            // 128 x 32
        unsigned short* AlS = smem + 4096;
        unsigned short* BhS = smem + 8192;
        unsigned short* BlS = smem + 12288;
        const int srow = lane >> 2;
        const int sc8  = (lane & 3) * 8;

        for (int kt = 0; kt < HID / 32; ++kt) {
            const int k0 = kt * 32;
            __syncthreads();
#pragma unroll
            for (int it = 0; it < 2; ++it) {
                const int rA = wave * 32 + it * 16;
                const size_t gro = (size_t)(rowBase + rA + srow) * HID + k0 + sc8;
                const size_t gco = (size_t)(colBase + rA + srow) * HID + k0 + sc8;
                lds_load16(&AhS[rA * 32], &Ah[gro]);
                lds_load16(&BhS[rA * 32], &Bh[gco]);
                lds_load16(&AlS[rA * 32], &Al[gro]);
                lds_load16(&BlS[rA * 32], &Bl[gco]);
            }
            __syncthreads();

            s8v afh[4], afl[4], bfh[4], bfl[4];
#pragma unroll
            for (int mf = 0; mf < 4; ++mf) {
                afh[mf] = *(const s8v*)&AhS[(wm * 64 + mf * 16 + l15) * 32 + quad * 8];
                afl[mf] = *(const s8v*)&AlS[(wm * 64 + mf * 16 + l15) * 32 + quad * 8];
            }
#pragma unroll
            for (int nf = 0; nf < 4; ++nf) {
                bfh[nf] = *(const s8v*)&BhS[(wn * 64 + nf * 16 + l15) * 32 + quad * 8];
                bfl[nf] = *(const s8v*)&BlS[(wn * 64 + nf * 16 + l15) * 32 + quad * 8];
            }
#pragma unroll
            for (int mf = 0; mf < 4; ++mf)
#pragma unroll
                for (int nf = 0; nf < 4; ++nf) {
                    acc[mf][nf] = __builtin_amdgcn_mfma_f32_16x16x32_bf16(afh[mf], bfh[nf], acc[mf][nf], 0, 0, 0);
                    acc[mf][nf] = __builtin_amdgcn_mfma_f32_16x16x32_bf16(afh[mf], bfl[nf], acc[mf][nf], 0, 0, 0);
                    acc[mf][nf] = __builtin_amdgcn_mfma_f32_16x16x32_bf16(afl[mf], bfh[nf], acc[mf][nf], 0, 0, 0);
                }
        }
    } else {
        // ---------- 1-term K/V path, BK=64, XOR-swizzled ----------
        unsigned short* AS = smem;            // 128 x 64
        unsigned short* BS = smem + 8192;
        const int srow8 = lane >> 3;          // 8 rows per 1KB instr-slice
        const int sc    = lane & 7;

        for (int kt = 0; kt < HID / 64; ++kt) {
            const int k0 = kt * 64;
            __syncthreads();
#pragma unroll
            for (int it = 0; it < 4; ++it) {
                const int i = wave * 4 + it;
                const int row = i * 8 + srow8;
                const int gx = (sc ^ (row & 7)) * 8;
                lds_load16(&AS[i * 512], &Ah[(size_t)(rowBase + row) * HID + k0 + gx]);
                lds_load16(&BS[i * 512], &Bh[(size_t)(colBase + row) * HID + k0 + gx]);
            }
            __syncthreads();

#pragma unroll
            for (int kk = 0; kk < 2; ++kk) {
                s8v af[4], bf[4];
#pragma unroll
                for (int mf = 0; mf < 4; ++mf)
                    af[mf] = *(const s8v*)&AS[(wm * 64 + mf * 16 + l15) * 64 + (((kk * 4 + quad) ^ sw) * 8)];
#pragma unroll
                for (int nf = 0; nf < 4; ++nf)
                    bf[nf] = *(const s8v*)&BS[(wn * 64 + nf * 16 + l15) * 64 + (((kk * 4 + quad) ^ sw) * 8)];
#pragma unroll
                for (int mf = 0; mf < 4; ++mf)
#pragma unroll
                    for (int nf = 0; nf < 4; ++nf)
                        acc[mf][nf] = __builtin_amdgcn_mfma_f32_16x16x32_bf16(af[mf], bf[nf], acc[mf][nf], 0, 0, 0);
            }
        }
    }

    // ---- epilogue ----
#pragma unroll
    for (int nf = 0; nf < 4; ++nf) {
        const int n = colBase + wn * 64 + nf * 16 + l15;
        const float bb = bias[n];
        const int h = n >> 6, d = n & 63;
#pragma unroll
        for (int mf = 0; mf < 4; ++mf) {
            const int rw0 = rowBase + wm * 64 + mf * 16 + quad * 4;
            const int b = rw0 >> 11;
            const int s0 = rw0 & (SEQ - 1);
            float c[4];
#pragma unroll
            for (int r = 0; r < 4; ++r) c[r] = acc[mf][nf][r] + bb;
            if (z == 0) {
#pragma unroll
                for (int r = 0; r < 4; ++r) {
                    float q = c[r] * QSCALE;   // exp2-domain prescale
                    const size_t base = ((size_t)(b * NHEADS + h) * SEQ + s0 + r) * HDIM + d;
                    unsigned short hh = f2bf(q);
                    Qhi[base] = hh;
                    Qlo[base] = f2bf(q - bf2f(hh));
                }
            } else if (z == 1) {
#pragma unroll
                for (int r = 0; r < 4; ++r) {
                    const size_t base = ((size_t)(b * NHEADS + h) * SEQ + s0 + r) * HDIM + d;
                    Khi[base] = f2bf(c[r]);
                }
            } else {
                union { unsigned int w[2]; unsigned long long q; } pk;
                pk.w[0] = pkbf(c[0], c[1]);
                pk.w[1] = pkbf(c[2], c[3]);
                *(unsigned long long*)&VTg[((size_t)(b * NHEADS + h) * HDIM + d) * SEQ + s0] = pk.q;
            }
        }
    }
}

// ---------------- Stage 2: MFMA flash attention v5 (dbuf, 1 barrier/step) ----
// 4 waves x 32 q = 128 q/block, grid (32 bh, 16). K/V double-buffered via
// global_load_lds: prefetch kt+1 into alternate buffer BEFORE computing kt ->
// one barrier per step, staging latency hidden behind compute.
// p = exp2(s)*mask (Q prescaled by log2e); l from ROUNDED p.
#define BC 64

__global__ __launch_bounds__(256, 3) void attn_mfma_kernel(
    const unsigned short* __restrict__ Qhi, const unsigned short* __restrict__ Qlo,
    const unsigned short* __restrict__ Khi, const unsigned short* __restrict__ VTg,
    const float* __restrict__ mask, float* __restrict__ out)
{
    __shared__ unsigned short Kb[2][BC * HDIM];    // 2 x 8 KB, swizzled
    __shared__ unsigned short Vb[2][BC * HDIM];    // 2 x 8 KB, swizzled (V^T)
    __shared__ unsigned short Pbuf[4][32 * BC];    // 16 KB, per-wave, swizzled

    const int t = threadIdx.x;
    const int wave = t >> 6, lane = t & 63, quad = lane >> 4, l15 = lane & 15;
    const int sw = l15 & 7;
    const int bh = blockIdx.x, b = bh >> 4, h = bh & (NHEADS - 1);
    const int qbase = blockIdx.y * 128 + wave * 32;

    const size_t hb = (size_t)bh * SEQ * HDIM;
    const unsigned short* kbase = Khi + hb;
    const unsigned short* vbase = VTg + hb;
    const float* mrow = mask + b * SEQ;

    // Q B-frags in registers: lane n=l15 -> q, k = ds*32+quad*8+j.
    s8v qh[2][2], ql[2][2];
#pragma unroll
    for (int qf = 0; qf < 2; ++qf)
#pragma unroll
        for (int ds = 0; ds < 2; ++ds) {
            size_t off = hb + (size_t)(qbase + qf * 16 + l15) * HDIM + ds * 32 + quad * 8;
            qh[qf][ds] = *(const s8v*)&Qhi[off];
            ql[qf][ds] = *(const s8v*)&Qlo[off];
        }

    f4v oacc[2][4];
#pragma unroll
    for (int qf = 0; qf < 2; ++qf)
#pragma unroll
        for (int nf = 0; nf < 4; ++nf) oacc[qf][nf] = (f4v){0.f, 0.f, 0.f, 0.f};
    float l_r[2] = {0.f, 0.f};

    // staging: 8 slices per array, 2 per wave; lane -> (row in slice, chunk)
    const int srow8 = lane >> 3;
    const int sc    = lane & 7;
    // lane-invariant offsets (elems)
    int koff[2], voff[2];
#pragma unroll
    for (int it = 0; it < 2; ++it) {
        const int row = (wave * 2 + it) * 8 + srow8;
        const int gx = (sc ^ (row & 7)) * 8;
        koff[it] = row * HDIM + gx;
        voff[it] = row * SEQ + gx;
    }

    // prologue: stage tile 0 into buf 0
#pragma unroll
    for (int it = 0; it < 2; ++it) {
        const int i = wave * 2 + it;
        lds_load16(&Kb[0][i * 512], kbase + koff[it]);
        lds_load16(&Vb[0][i * 512], vbase + voff[it]);
    }
    __syncthreads();

    for (int kt = 0; kt < SEQ / BC; ++kt) {
        const int cur = kt & 1;
        // prefetch next tile into alternate buffer (consumed-next-step; the
        // barrier at the END of this step drains vmcnt before anyone reads it)
        if (kt + 1 < SEQ / BC) {
            const int nxt = cur ^ 1;
#pragma unroll
            for (int it = 0; it < 2; ++it) {
                const int i = wave * 2 + it;
                lds_load16(&Kb[nxt][i * 512], kbase + (kt + 1) * BC * HDIM + koff[it]);
                lds_load16(&Vb[nxt][i * 512], vbase + (kt + 1) * BC + voff[it]);
            }
        }
        // mask: 16-lane-broadcast float4 loads (L1/L2 resident)
        float4 msv[4];
#pragma unroll
        for (int mf = 0; mf < 4; ++mf)
            msv[mf] = *(const float4*)&mrow[kt * BC + mf * 16 + quad * 4];

        // ---- S^T = K.Q^T, 2-term: A = Khi frags (swizzled), B = Q regs ----
        f4v sacc[2][4];
#pragma unroll
        for (int qf = 0; qf < 2; ++qf)
#pragma unroll
            for (int mf = 0; mf < 4; ++mf) sacc[qf][mf] = (f4v){0.f, 0.f, 0.f, 0.f};
#pragma unroll
        for (int mf = 0; mf < 4; ++mf) {
#pragma unroll
            for (int ds = 0; ds < 2; ++ds) {
                s8v kh = *(const s8v*)&Kb[cur][(mf * 16 + l15) * HDIM + (((ds * 4 + quad) ^ sw) * 8)];
#pragma unroll
                for (int qf = 0; qf < 2; ++qf) {
                    sacc[qf][mf] = __builtin_amdgcn_mfma_f32_16x16x32_bf16(kh, qh[qf][ds], sacc[qf][mf], 0, 0, 0);
                    sacc[qf][mf] = __builtin_amdgcn_mfma_f32_16x16x32_bf16(kh, ql[qf][ds], sacc[qf][mf], 0, 0, 0);
                }
            }
        }

        // ---- p = exp2(s) * mask; pack; l from ROUNDED p ----
#pragma unroll
        for (int qf = 0; qf < 2; ++qf) {
            float psum = 0.f;
            const int prow = (qf * 16 + l15) * BC;
#pragma unroll
            for (int mf = 0; mf < 4; ++mf) {
                const float* mp = (const float*)&msv[mf];
                float p0 = __builtin_amdgcn_exp2f(sacc[qf][mf][0]) * mp[0];
                float p1 = __builtin_amdgcn_exp2f(sacc[qf][mf][1]) * mp[1];
                float p2 = __builtin_amdgcn_exp2f(sacc[qf][mf][2]) * mp[2];
                float p3 = __builtin_amdgcn_exp2f(sacc[qf][mf][3]) * mp[3];
                union { unsigned int w[2]; unsigned long long q; } pk;
                pk.w[0] = pkbf(p0, p1);
                pk.w[1] = pkbf(p2, p3);
                psum += bflo(pk.w[0]) + bfhi(pk.w[0]) + bflo(pk.w[1]) + bfhi(pk.w[1]);
                const int c16 = (mf * 2 + (quad >> 1)) ^ sw;
                *(unsigned long long*)&Pbuf[wave][prow + c16 * 8 + (quad & 1) * 4] = pk.q;
            }
            l_r[qf] += psum;
        }
        // no barrier: Pbuf is wave-private

        // ---- PV: A = P frags, B = V^T frags (both swizzled) ----
#pragma unroll
        for (int ks = 0; ks < 2; ++ks) {
            const int csw = ((ks * 4 + quad) ^ sw) * 8;
            s8v pa0 = *(const s8v*)&Pbuf[wave][(0 * 16 + l15) * BC + csw];
            s8v pa1 = *(const s8v*)&Pbuf[wave][(1 * 16 + l15) * BC + csw];
#pragma unroll
            for (int nf = 0; nf < 4; ++nf) {
                s8v vb = *(const s8v*)&Vb[cur][(nf * 16 + l15) * BC + csw];
                oacc[0][nf] = __builtin_amdgcn_mfma_f32_16x16x32_bf16(pa0, vb, oacc[0][nf], 0, 0, 0);
                oacc[1][nf] = __builtin_amdgcn_mfma_f32_16x16x32_bf16(pa1, vb, oacc[1][nf], 0, 0, 0);
            }
        }
        __syncthreads();   // done reading cur; next-tile loads drained
    }

    // ---- epilogue: quad-reduce l, normalize, write [b][s][h*64+d] ----
#pragma unroll
    for (int qf = 0; qf < 2; ++qf) {
        float v = l_r[qf];
        v += __shfl_xor(v, 16);
        v += __shfl_xor(v, 32);
        float lv[4];
#pragma unroll
        for (int r = 0; r < 4; ++r)
            lv[r] = 1.0f / __shfl(v, quad * 4 + r);
#pragma unroll
        for (int nf = 0; nf < 4; ++nf)
#pragma unroll
            for (int r = 0; r < 4; ++r) {
                int q = qbase + qf * 16 + quad * 4 + r;
                int d = nf * 16 + l15;
                out[((size_t)b * SEQ + q) * HID + h * HDIM + d] = oacc[qf][nf][r] * lv[r];
            }
    }
}

extern "C" void kernel_launch(void* const* d_in, const int* in_sizes, int n_in,
                              void* d_out, int out_size, void* d_ws, size_t ws_size,
                              hipStream_t stream) {
    const float* hs   = (const float*)d_in[0];
    const float* mask = (const float*)d_in[1];
    const float* Wq   = (const float*)d_in[2];
    const float* bq   = (const float*)d_in[3];
    const float* Wk   = (const float*)d_in[4];
    const float* bk   = (const float*)d_in[5];
    const float* Wv   = (const float*)d_in[6];
    const float* bv   = (const float*)d_in[7];
    float* out = (float*)d_out;

    const size_t N = (size_t)MROWS * HID;        // 4.19M u16 per array
    const size_t WN = (size_t)3 * HID * HID;
    unsigned short* Qhi = (unsigned short*)d_ws;
    unsigned short* Qlo = Qhi + N;
    unsigned short* Khi = Qhi + 2 * N;
    unsigned short* VTg = Qhi + 3 * N;
    unsigned short* Ah  = Qhi + 4 * N;
    unsigned short* Al  = Qhi + 5 * N;
    unsigned short* WTh = Qhi + 6 * N;
    unsigned short* WTl = WTh + WN;

    conv_hs_kernel<<<(MROWS * HID) / (256 * 4), 256, 0, stream>>>(hs, Ah, Al);
    conv_wt_kernel<<<dim3(HID / 64, HID / 64, 3), 256, 0, stream>>>(Wq, Wk, Wv, WTh, WTl);

    dim3 g1(MROWS / GBM, HID / GBN, 3);   // 32 x 8 x 3 (M-major: A-sharing on one XCD)
    qkv_mfma_kernel<<<g1, 256, 0, stream>>>(Ah, Al, WTh, WTl, bq, bk, bv,
                                            Qhi, Qlo, Khi, VTg);

    dim3 g2(BHT, SEQ / 128);              // 32 x 16 (bh-major: K/V stay in one XCD's L2)
    attn_mfma_kernel<<<g2, 256, 0, stream>>>(Qhi, Qlo, Khi, VTg, mask, out);
}

// Round 8
// 184.914 us; speedup vs baseline: 1.1545x; 1.1545x over previous
//
#include <hip/hip_runtime.h>
#include <hip/hip_bf16.h>
#include <cstddef>
#include <cstdint>

#define HID 1024
#define NHEADS 16
#define HDIM 64
#define BATCH 2
#define SEQ 2048
#define MROWS (BATCH * SEQ)   // 4096
#define BHT (BATCH * NHEADS)  // 32

typedef __attribute__((ext_vector_type(8))) short s8v;   // 8 x bf16 (4 VGPR)
typedef __attribute__((ext_vector_type(4))) float f4v;   // MFMA C/D frag

__device__ __forceinline__ unsigned short f2bf(float x) {
    union { float f; unsigned int u; } c; c.f = x;
    return (unsigned short)((c.u + 0x7fffu + ((c.u >> 16) & 1u)) >> 16);  // RTN
}
__device__ __forceinline__ unsigned int pkbf(float a, float b) {
    __hip_bfloat162 h = __float22bfloat162_rn(float2{a, b});  // x -> low 16
    union { __hip_bfloat162 v; unsigned int u; } c; c.v = h; return c.u;
}
__device__ __forceinline__ float bflo(unsigned int w) {
    union { unsigned int u; float f; } c; c.u = w << 16; return c.f;
}
__device__ __forceinline__ float bfhi(unsigned int w) {
    union { unsigned int u; float f; } c; c.u = w & 0xffff0000u; return c.f;
}

__device__ __forceinline__ void lds_load16(void* lds, const void* g) {
    __builtin_amdgcn_global_load_lds(
        (const __attribute__((address_space(1))) void*)g,
        (__attribute__((address_space(3))) void*)lds, 16, 0, 0);
}

// ---------------- Stage 0a: hs fp32 -> bf16, layout [m][k] ----------------
__global__ __launch_bounds__(256) void conv_hs_kernel(
    const float* __restrict__ hs, unsigned short* __restrict__ Ah)
{
    const int idx = (blockIdx.x * 256 + threadIdx.x) * 4;
    float4 v = *(const float4*)&hs[idx];
    union { unsigned int w[2]; unsigned long long q; } pk;
    pk.w[0] = pkbf(v.x, v.y);
    pk.w[1] = pkbf(v.z, v.w);
    *(unsigned long long*)&Ah[idx] = pk.q;
}

// ---------------- Stage 0b: W [k][n] -> W^T [n][k] bf16 ----------------
__global__ __launch_bounds__(256) void conv_wt_kernel(
    const float* __restrict__ Wq, const float* __restrict__ Wk,
    const float* __restrict__ Wv, unsigned short* __restrict__ WTh)
{
    const int z = blockIdx.z;
    const float* W = (z == 0) ? Wq : (z == 1) ? Wk : Wv;
    unsigned short* th = WTh + (size_t)z * HID * HID;

    __shared__ float tile[64][65];
    const int t = threadIdx.x;
    const int kb = blockIdx.y * 64, nb = blockIdx.x * 64;
    const int c4 = (t & 15) * 4;
    const int r0 = t >> 4;

#pragma unroll
    for (int i = 0; i < 4; ++i) {
        int r = r0 + i * 16;
        float4 v = *(const float4*)&W[(size_t)(kb + r) * HID + nb + c4];
        tile[r][c4 + 0] = v.x; tile[r][c4 + 1] = v.y;
        tile[r][c4 + 2] = v.z; tile[r][c4 + 3] = v.w;
    }
    __syncthreads();
#pragma unroll
    for (int i = 0; i < 4; ++i) {
        int n = r0 + i * 16;
        union { unsigned int w[2]; unsigned long long q; } pk;
        pk.w[0] = pkbf(tile[c4 + 0][n], tile[c4 + 1][n]);
        pk.w[1] = pkbf(tile[c4 + 2][n], tile[c4 + 3][n]);
        *(unsigned long long*)&th[(size_t)(nb + n) * HID + kb + c4] = pk.q;
    }
}

// ---------------- Stage 1: QKV projection, 1-term bf16 MFMA, BK=64 ----------
// z=0 (Q): out Qg [bh][s][d], prescaled 0.125*log2(e) (exp2 domain).
// z=1 (K): out Khi [bh][s][d].
// z=2 (V): out VT [bh][d][s] (transposed for attention B-frags).
#define GBM 128
#define GBN 128
#define QSCALE 0.18033688011112042f   // 0.125 * log2(e)

__global__ __launch_bounds__(256) void qkv_mfma_kernel(
    const unsigned short* __restrict__ Ah, const unsigned short* __restrict__ WTh,
    const float* __restrict__ bq, const float* __restrict__ bk,
    const float* __restrict__ bv,
    unsigned short* __restrict__ Qg, unsigned short* __restrict__ Khi,
    unsigned short* __restrict__ VTg)
{
    const int z = blockIdx.z;
    const float* bias = (z == 0) ? bq : (z == 1) ? bk : bv;
    const unsigned short* Bh = WTh + (size_t)z * HID * HID;

    __shared__ unsigned short AS[GBM * 64];   // 16 KB, XOR-swizzled rows
    __shared__ unsigned short BS[GBN * 64];   // 16 KB

    const int t = threadIdx.x;
    const int wave = t >> 6, lane = t & 63, quad = lane >> 4, l15 = lane & 15;
    const int sw = l15 & 7;
    const int wm = wave >> 1, wn = wave & 1;
    const int rowBase = blockIdx.x * GBM;   // M tile (x-major: A-sharing on one XCD)
    const int colBase = blockIdx.y * GBN;   // N tile

    const int srow8 = lane >> 3;            // 8 rows per 1KB instr-slice
    const int sc    = lane & 7;

    f4v acc[4][4];
#pragma unroll
    for (int mf = 0; mf < 4; ++mf)
#pragma unroll
        for (int nf = 0; nf < 4; ++nf) acc[mf][nf] = (f4v){0.f, 0.f, 0.f, 0.f};

    for (int kt = 0; kt < HID / 64; ++kt) {
        const int k0 = kt * 64;
        __syncthreads();
#pragma unroll
        for (int it = 0; it < 4; ++it) {
            const int i = wave * 4 + it;
            const int row = i * 8 + srow8;
            const int gx = (sc ^ (row & 7)) * 8;
            lds_load16(&AS[i * 512], &Ah[(size_t)(rowBase + row) * HID + k0 + gx]);
            lds_load16(&BS[i * 512], &Bh[(size_t)(colBase + row) * HID + k0 + gx]);
        }
        __syncthreads();

#pragma unroll
        for (int kk = 0; kk < 2; ++kk) {
            s8v af[4], bf[4];
#pragma unroll
            for (int mf = 0; mf < 4; ++mf)
                af[mf] = *(const s8v*)&AS[(wm * 64 + mf * 16 + l15) * 64 + (((kk * 4 + quad) ^ sw) * 8)];
#pragma unroll
            for (int nf = 0; nf < 4; ++nf)
                bf[nf] = *(const s8v*)&BS[(wn * 64 + nf * 16 + l15) * 64 + (((kk * 4 + quad) ^ sw) * 8)];
#pragma unroll
            for (int mf = 0; mf < 4; ++mf)
#pragma unroll
                for (int nf = 0; nf < 4; ++nf)
                    acc[mf][nf] = __builtin_amdgcn_mfma_f32_16x16x32_bf16(af[mf], bf[nf], acc[mf][nf], 0, 0, 0);
        }
    }

    // ---- epilogue ----
#pragma unroll
    for (int nf = 0; nf < 4; ++nf) {
        const int n = colBase + wn * 64 + nf * 16 + l15;
        const float bb = bias[n];
        const int h = n >> 6, d = n & 63;
#pragma unroll
        for (int mf = 0; mf < 4; ++mf) {
            const int rw0 = rowBase + wm * 64 + mf * 16 + quad * 4;
            const int b = rw0 >> 11;
            const int s0 = rw0 & (SEQ - 1);
            float c[4];
#pragma unroll
            for (int r = 0; r < 4; ++r) c[r] = acc[mf][nf][r] + bb;
            if (z == 0) {
#pragma unroll
                for (int r = 0; r < 4; ++r) {
                    const size_t base = ((size_t)(b * NHEADS + h) * SEQ + s0 + r) * HDIM + d;
                    Qg[base] = f2bf(c[r] * QSCALE);   // exp2-domain prescale
                }
            } else if (z == 1) {
#pragma unroll
                for (int r = 0; r < 4; ++r) {
                    const size_t base = ((size_t)(b * NHEADS + h) * SEQ + s0 + r) * HDIM + d;
                    Khi[base] = f2bf(c[r]);
                }
            } else {
                union { unsigned int w[2]; unsigned long long q; } pk;
                pk.w[0] = pkbf(c[0], c[1]);
                pk.w[1] = pkbf(c[2], c[3]);
                *(unsigned long long*)&VTg[((size_t)(b * NHEADS + h) * HDIM + d) * SEQ + s0] = pk.q;
            }
        }
    }
}

// ---------------- Stage 2: MFMA flash attention v6 (1-term Q, dbuf) ----------
// 4 waves x 32 q = 128 q/block, grid (32 bh, 16). K/V double-buffered via
// global_load_lds, one barrier per step. S = K.Q^T single-term bf16.
// p = exp2(s)*mask (Q prescaled by log2e); l from ROUNDED p.
#define BC 64

__global__ __launch_bounds__(256, 2) void attn_mfma_kernel(
    const unsigned short* __restrict__ Qg, const unsigned short* __restrict__ Khi,
    const unsigned short* __restrict__ VTg,
    const float* __restrict__ mask, float* __restrict__ out)
{
    __shared__ unsigned short Kb[2][BC * HDIM];    // 2 x 8 KB, swizzled
    __shared__ unsigned short Vb[2][BC * HDIM];    // 2 x 8 KB, swizzled (V^T)
    __shared__ unsigned short Pbuf[4][32 * BC];    // 16 KB, per-wave, swizzled

    const int t = threadIdx.x;
    const int wave = t >> 6, lane = t & 63, quad = lane >> 4, l15 = lane & 15;
    const int sw = l15 & 7;
    const int bh = blockIdx.x, b = bh >> 4, h = bh & (NHEADS - 1);
    const int qbase = blockIdx.y * 128 + wave * 32;

    const size_t hb = (size_t)bh * SEQ * HDIM;
    const unsigned short* kbase = Khi + hb;
    const unsigned short* vbase = VTg + hb;
    const float* mrow = mask + b * SEQ;

    // Q B-frags in registers: lane n=l15 -> q, k = ds*32+quad*8+j.
    s8v qh[2][2];
#pragma unroll
    for (int qf = 0; qf < 2; ++qf)
#pragma unroll
        for (int ds = 0; ds < 2; ++ds) {
            size_t off = hb + (size_t)(qbase + qf * 16 + l15) * HDIM + ds * 32 + quad * 8;
            qh[qf][ds] = *(const s8v*)&Qg[off];
        }

    f4v oacc[2][4];
#pragma unroll
    for (int qf = 0; qf < 2; ++qf)
#pragma unroll
        for (int nf = 0; nf < 4; ++nf) oacc[qf][nf] = (f4v){0.f, 0.f, 0.f, 0.f};
    float l_r[2] = {0.f, 0.f};

    // staging: 8 slices per array, 2 per wave; lane -> (row in slice, chunk)
    const int srow8 = lane >> 3;
    const int sc    = lane & 7;
    int koff[2], voff[2];
#pragma unroll
    for (int it = 0; it < 2; ++it) {
        const int row = (wave * 2 + it) * 8 + srow8;
        const int gx = (sc ^ (row & 7)) * 8;
        koff[it] = row * HDIM + gx;
        voff[it] = row * SEQ + gx;
    }

    // prologue: stage tile 0 into buf 0
#pragma unroll
    for (int it = 0; it < 2; ++it) {
        const int i = wave * 2 + it;
        lds_load16(&Kb[0][i * 512], kbase + koff[it]);
        lds_load16(&Vb[0][i * 512], vbase + voff[it]);
    }
    __syncthreads();

    for (int kt = 0; kt < SEQ / BC; ++kt) {
        const int cur = kt & 1;
        if (kt + 1 < SEQ / BC) {
            const int nxt = cur ^ 1;
#pragma unroll
            for (int it = 0; it < 2; ++it) {
                const int i = wave * 2 + it;
                lds_load16(&Kb[nxt][i * 512], kbase + (kt + 1) * BC * HDIM + koff[it]);
                lds_load16(&Vb[nxt][i * 512], vbase + (kt + 1) * BC + voff[it]);
            }
        }
        float4 msv[4];
#pragma unroll
        for (int mf = 0; mf < 4; ++mf)
            msv[mf] = *(const float4*)&mrow[kt * BC + mf * 16 + quad * 4];

        // ---- S^T = K.Q^T, 1-term: A = Khi frags (swizzled), B = Q regs ----
        f4v sacc[2][4];
#pragma unroll
        for (int qf = 0; qf < 2; ++qf)
#pragma unroll
            for (int mf = 0; mf < 4; ++mf) sacc[qf][mf] = (f4v){0.f, 0.f, 0.f, 0.f};
#pragma unroll
        for (int mf = 0; mf < 4; ++mf) {
#pragma unroll
            for (int ds = 0; ds < 2; ++ds) {
                s8v kh = *(const s8v*)&Kb[cur][(mf * 16 + l15) * HDIM + (((ds * 4 + quad) ^ sw) * 8)];
#pragma unroll
                for (int qf = 0; qf < 2; ++qf)
                    sacc[qf][mf] = __builtin_amdgcn_mfma_f32_16x16x32_bf16(kh, qh[qf][ds], sacc[qf][mf], 0, 0, 0);
            }
        }

        // ---- p = exp2(s) * mask; pack; l from ROUNDED p ----
#pragma unroll
        for (int qf = 0; qf < 2; ++qf) {
            float psum = 0.f;
            const int prow = (qf * 16 + l15) * BC;
#pragma unroll
            for (int mf = 0; mf < 4; ++mf) {
                const float* mp = (const float*)&msv[mf];
                float p0 = __builtin_amdgcn_exp2f(sacc[qf][mf][0]) * mp[0];
                float p1 = __builtin_amdgcn_exp2f(sacc[qf][mf][1]) * mp[1];
                float p2 = __builtin_amdgcn_exp2f(sacc[qf][mf][2]) * mp[2];
                float p3 = __builtin_amdgcn_exp2f(sacc[qf][mf][3]) * mp[3];
                union { unsigned int w[2]; unsigned long long q; } pk;
                pk.w[0] = pkbf(p0, p1);
                pk.w[1] = pkbf(p2, p3);
                psum += bflo(pk.w[0]) + bfhi(pk.w[0]) + bflo(pk.w[1]) + bfhi(pk.w[1]);
                const int c16 = (mf * 2 + (quad >> 1)) ^ sw;
                *(unsigned long long*)&Pbuf[wave][prow + c16 * 8 + (quad & 1) * 4] = pk.q;
            }
            l_r[qf] += psum;
        }
        // no barrier: Pbuf is wave-private

        // ---- PV: A = P frags, B = V^T frags (both swizzled) ----
#pragma unroll
        for (int ks = 0; ks < 2; ++ks) {
            const int csw = ((ks * 4 + quad) ^ sw) * 8;
            s8v pa0 = *(const s8v*)&Pbuf[wave][(0 * 16 + l15) * BC + csw];
            s8v pa1 = *(const s8v*)&Pbuf[wave][(1 * 16 + l15) * BC + csw];
#pragma unroll
            for (int nf = 0; nf < 4; ++nf) {
                s8v vb = *(const s8v*)&Vb[cur][(nf * 16 + l15) * BC + csw];
                oacc[0][nf] = __builtin_amdgcn_mfma_f32_16x16x32_bf16(pa0, vb, oacc[0][nf], 0, 0, 0);
                oacc[1][nf] = __builtin_amdgcn_mfma_f32_16x16x32_bf16(pa1, vb, oacc[1][nf], 0, 0, 0);
            }
        }
        __syncthreads();   // done reading cur; next-tile loads drained
    }

    // ---- epilogue: quad-reduce l, normalize, write [b][s][h*64+d] ----
#pragma unroll
    for (int qf = 0; qf < 2; ++qf) {
        float v = l_r[qf];
        v += __shfl_xor(v, 16);
        v += __shfl_xor(v, 32);
        float lv[4];
#pragma unroll
        for (int r = 0; r < 4; ++r)
            lv[r] = 1.0f / __shfl(v, quad * 4 + r);
#pragma unroll
        for (int nf = 0; nf < 4; ++nf)
#pragma unroll
            for (int r = 0; r < 4; ++r) {
                int q = qbase + qf * 16 + quad * 4 + r;
                int d = nf * 16 + l15;
                out[((size_t)b * SEQ + q) * HID + h * HDIM + d] = oacc[qf][nf][r] * lv[r];
            }
    }
}

extern "C" void kernel_launch(void* const* d_in, const int* in_sizes, int n_in,
                              void* d_out, int out_size, void* d_ws, size_t ws_size,
                              hipStream_t stream) {
    const float* hs   = (const float*)d_in[0];
    const float* mask = (const float*)d_in[1];
    const float* Wq   = (const float*)d_in[2];
    const float* bq   = (const float*)d_in[3];
    const float* Wk   = (const float*)d_in[4];
    const float* bk   = (const float*)d_in[5];
    const float* Wv   = (const float*)d_in[6];
    const float* bv   = (const float*)d_in[7];
    float* out = (float*)d_out;

    const size_t N = (size_t)MROWS * HID;        // 4.19M u16 per array
    unsigned short* Qg  = (unsigned short*)d_ws;
    unsigned short* Khi = Qg + N;
    unsigned short* VTg = Qg + 2 * N;
    unsigned short* Ah  = Qg + 3 * N;
    unsigned short* WTh = Qg + 4 * N;            // 3*HID*HID u16

    conv_hs_kernel<<<(MROWS * HID) / (256 * 4), 256, 0, stream>>>(hs, Ah);
    conv_wt_kernel<<<dim3(HID / 64, HID / 64, 3), 256, 0, stream>>>(Wq, Wk, Wv, WTh);

    dim3 g1(MROWS / GBM, HID / GBN, 3);   // 32 x 8 x 3 (M-major: A-sharing on one XCD)
    qkv_mfma_kernel<<<g1, 256, 0, stream>>>(Ah, WTh, bq, bk, bv, Qg, Khi, VTg);

    dim3 g2(BHT, SEQ / 128);              // 32 x 16 (bh-major: K/V stay in one XCD's L2)
    attn_mfma_kernel<<<g2, 256, 0, stream>>>(Qg, Khi, VTg, mask, out);
}